// Round 1
// baseline (42.305 us; speedup 1.0000x reference)
//
#include <hip/hip_runtime.h>

#define B_    1024
#define NIN_  126
#define NOUT_ 126
#define K_    3
#define H1_   256
#define H2_   256
#define RPB   4      // batch rows per block
#define TPB   256

__device__ __forceinline__ float elu1(float v) { return v > 0.0f ? v : expm1f(v); }

__global__ __launch_bounds__(TPB, 1) void bim_fused(
    const float* __restrict__ x,  const float* __restrict__ W0,
    const float* __restrict__ b0, const float* __restrict__ W1,
    const float* __restrict__ b1, const float* __restrict__ W2,
    const float* __restrict__ b2, const int*  __restrict__ iidx,
    const int*  __restrict__ oidx, float* __restrict__ out)
{
    __shared__ float xe [RPB][128];   // scattered x (pad index 126 dropped)
    __shared__ float h1s[RPB][H1_];
    __shared__ float h2s[RPB][H2_];
    __shared__ float ts [RPB][128];   // t[b,j] = h2 . W2[j,:]

    const int tid  = threadIdx.x;
    const int row0 = blockIdx.x * RPB;

    // ---- phase A: zero xe, scatter-accumulate x by batch_in_index ----
    for (int n = tid; n < RPB * 128; n += TPB) (&xe[0][0])[n] = 0.0f;
    __syncthreads();

    for (int n = tid; n < RPB * NIN_ * K_; n += TPB) {
        const int r = n / (NIN_ * K_);
        const int m = n - r * (NIN_ * K_);
        const int i = m / K_;
        const int j = iidx[(row0 + r) * (NIN_ * K_) + m];
        if (j < NIN_) atomicAdd(&xe[r][j], x[(row0 + r) * NIN_ + i]);
    }
    __syncthreads();

    // ---- phase B: h1 = elu(xe @ W0^T + b0); thread o owns column o ----
    {
        const int o = tid;
        float acc[RPB];
        #pragma unroll
        for (int r = 0; r < RPB; ++r) acc[r] = 0.0f;
        // W0 row o is 126 contiguous floats; 8B-aligned always (o*504 % 8 == 0)
        const float2* wr = reinterpret_cast<const float2*>(W0 + o * NIN_);
        for (int ii = 0; ii < NIN_ / 2; ++ii) {
            const float2 w = wr[ii];
            #pragma unroll
            for (int r = 0; r < RPB; ++r) {
                const float2 a = *reinterpret_cast<const float2*>(&xe[r][2 * ii]);
                acc[r] = fmaf(a.x, w.x, acc[r]);
                acc[r] = fmaf(a.y, w.y, acc[r]);
            }
        }
        const float bias = b0[o];
        #pragma unroll
        for (int r = 0; r < RPB; ++r) h1s[r][o] = elu1(acc[r] + bias);
    }
    __syncthreads();

    // ---- phase C: h2 = elu(h1 @ W1^T + b1) ----
    {
        const int o = tid;
        float acc[RPB];
        #pragma unroll
        for (int r = 0; r < RPB; ++r) acc[r] = 0.0f;
        const float4* wr = reinterpret_cast<const float4*>(W1 + o * H1_); // 1KB-aligned rows
        for (int ii = 0; ii < H1_ / 4; ++ii) {
            const float4 w = wr[ii];
            #pragma unroll
            for (int r = 0; r < RPB; ++r) {
                const float4 a = *reinterpret_cast<const float4*>(&h1s[r][4 * ii]);
                acc[r] = fmaf(a.x, w.x, acc[r]);
                acc[r] = fmaf(a.y, w.y, acc[r]);
                acc[r] = fmaf(a.z, w.z, acc[r]);
                acc[r] = fmaf(a.w, w.w, acc[r]);
            }
        }
        const float bias = b1[o];
        #pragma unroll
        for (int r = 0; r < RPB; ++r) h2s[r][o] = elu1(acc[r] + bias);
    }
    __syncthreads();

    // ---- phase D: ts[r][j] = h2s[r] . W2[j,:]  (504 tasks) ----
    for (int n = tid; n < RPB * NOUT_; n += TPB) {
        const int r = n / NOUT_;
        const int j = n - r * NOUT_;
        float acc = 0.0f;
        const float4* wr = reinterpret_cast<const float4*>(W2 + j * H2_); // 1KB-aligned rows
        for (int ii = 0; ii < H2_ / 4; ++ii) {
            const float4 w = wr[ii];
            const float4 a = *reinterpret_cast<const float4*>(&h2s[r][4 * ii]);
            acc = fmaf(a.x, w.x, acc);
            acc = fmaf(a.y, w.y, acc);
            acc = fmaf(a.z, w.z, acc);
            acc = fmaf(a.w, w.w, acc);
        }
        ts[r][j] = acc;
    }
    __syncthreads();

    // ---- phase E: out[b,o] = sum_k (j<126 ? ts[r][j] + b2[j] : 0) ----
    for (int n = tid; n < RPB * NOUT_; n += TPB) {
        const int r = n / NOUT_;
        const int o = n - r * NOUT_;
        const int base = (row0 + r) * (NOUT_ * K_) + o * K_;
        float v = 0.0f;
        #pragma unroll
        for (int k = 0; k < K_; ++k) {
            const int j = oidx[base + k];
            if (j < NOUT_) v += ts[r][j] + b2[j];
        }
        out[(row0 + r) * NOUT_ + o] = v;
    }
}

extern "C" void kernel_launch(void* const* d_in, const int* in_sizes, int n_in,
                              void* d_out, int out_size, void* d_ws, size_t ws_size,
                              hipStream_t stream) {
    const float* x   = (const float*)d_in[0];
    const float* W0  = (const float*)d_in[1];
    const float* b0  = (const float*)d_in[2];
    const float* W1  = (const float*)d_in[3];
    const float* b1  = (const float*)d_in[4];
    const float* W2  = (const float*)d_in[5];
    const float* b2  = (const float*)d_in[6];
    const int*  iidx = (const int*)d_in[7];
    const int*  oidx = (const int*)d_in[8];
    float* out = (float*)d_out;

    bim_fused<<<B_ / RPB, TPB, 0, stream>>>(x, W0, b0, W1, b1, W2, b2, iidx, oidx, out);
}

// Round 2
// 20.168 us; speedup vs baseline: 2.0977x; 2.0977x over previous
//
#include <hip/hip_runtime.h>

#define B_    1024
#define NIN_  126
#define NOUT_ 126
#define K_    3
#define H1_   256
#define H2_   256
#define RPB   4      // batch rows per block
#define TPB   512    // 8 waves

__device__ __forceinline__ float elu1(float v) { return v > 0.0f ? v : expm1f(v); }

// butterfly sum over 8 consecutive lanes (q = lane&7)
__device__ __forceinline__ float qsum8(float v) {
    v += __shfl_xor(v, 1);
    v += __shfl_xor(v, 2);
    v += __shfl_xor(v, 4);
    return v;
}

__global__ __launch_bounds__(TPB, 2) void bim_fused(
    const float* __restrict__ x,  const float* __restrict__ W0,
    const float* __restrict__ b0, const float* __restrict__ W1,
    const float* __restrict__ b1, const float* __restrict__ W2,
    const float* __restrict__ b2, const int*  __restrict__ iidx,
    const int*  __restrict__ oidx, float* __restrict__ out)
{
    __shared__ float xe [RPB][128];   // scattered x (index 126 = zero pad, dropped)
    __shared__ float h1s[RPB][H1_];
    __shared__ float h2s[RPB][H2_];
    __shared__ float ts [RPB][128];   // t[r][j] = h2[r] . W2[j,:]

    const int tid  = threadIdx.x;
    const int row0 = blockIdx.x * RPB;
    const int q    = tid & 7;   // j-subset within a group
    const int g    = tid >> 3;  // group id 0..63

    // ---- phase A: zero xe, scatter-accumulate x by batch_in_index ----
    for (int n = tid; n < RPB * 128; n += TPB) (&xe[0][0])[n] = 0.0f;
    __syncthreads();

    for (int n = tid; n < RPB * NIN_ * K_; n += TPB) {
        const int r = n / (NIN_ * K_);
        const int m = n - r * (NIN_ * K_);
        const int i = m / K_;
        const int j = iidx[(row0 + r) * (NIN_ * K_) + m];
        if (j < NIN_) atomicAdd(&xe[r][j], x[(row0 + r) * NIN_ + i]);
    }
    __syncthreads();

    // ---- phase B: h1 = elu(xe @ W0^T + b0) ----
    // group g owns outputs o = 4g..4g+3; lane q covers j = q*2 + jj*16 (float2)
    {
        float acc[4][4];  // [oo][r]
        #pragma unroll
        for (int oo = 0; oo < 4; ++oo)
            #pragma unroll
            for (int r = 0; r < 4; ++r) acc[oo][r] = 0.0f;

        const float* w0p = W0 + (g * 4) * NIN_;
        #pragma unroll
        for (int jj = 0; jj < 8; ++jj) {
            const int j = q * 2 + jj * 16;
            if (!(q == 7 && jj == 7)) {     // j==126 -> zero pad, skip (exact)
                float2 w[4], a[4];
                #pragma unroll
                for (int oo = 0; oo < 4; ++oo)
                    w[oo] = *reinterpret_cast<const float2*>(w0p + oo * NIN_ + j);
                #pragma unroll
                for (int r = 0; r < 4; ++r)
                    a[r] = *reinterpret_cast<const float2*>(&xe[r][j]);
                #pragma unroll
                for (int oo = 0; oo < 4; ++oo)
                    #pragma unroll
                    for (int r = 0; r < 4; ++r) {
                        acc[oo][r] = fmaf(w[oo].x, a[r].x, acc[oo][r]);
                        acc[oo][r] = fmaf(w[oo].y, a[r].y, acc[oo][r]);
                    }
            }
        }
        #pragma unroll
        for (int oo = 0; oo < 4; ++oo)
            #pragma unroll
            for (int r = 0; r < 4; ++r) acc[oo][r] = qsum8(acc[oo][r]);
        if (q == 0) {
            #pragma unroll
            for (int oo = 0; oo < 4; ++oo) {
                const int o = g * 4 + oo;
                const float bias = b0[o];
                #pragma unroll
                for (int r = 0; r < 4; ++r) h1s[r][o] = elu1(acc[oo][r] + bias);
            }
        }
    }
    __syncthreads();

    // ---- phase C: h2 = elu(h1 @ W1^T + b1) ----
    // group g owns o = 4g..4g+3; lane q covers j = q*4 + jj*32 (float4)
    {
        float acc[4][4];
        #pragma unroll
        for (int oo = 0; oo < 4; ++oo)
            #pragma unroll
            for (int r = 0; r < 4; ++r) acc[oo][r] = 0.0f;

        const float* w1p = W1 + (g * 4) * H1_;
        #pragma unroll
        for (int jj = 0; jj < 8; ++jj) {
            const int j = q * 4 + jj * 32;
            float4 w[4], a[4];
            #pragma unroll
            for (int oo = 0; oo < 4; ++oo)
                w[oo] = *reinterpret_cast<const float4*>(w1p + oo * H1_ + j);
            #pragma unroll
            for (int r = 0; r < 4; ++r)
                a[r] = *reinterpret_cast<const float4*>(&h1s[r][j]);
            #pragma unroll
            for (int oo = 0; oo < 4; ++oo)
                #pragma unroll
                for (int r = 0; r < 4; ++r) {
                    acc[oo][r] = fmaf(w[oo].x, a[r].x, acc[oo][r]);
                    acc[oo][r] = fmaf(w[oo].y, a[r].y, acc[oo][r]);
                    acc[oo][r] = fmaf(w[oo].z, a[r].z, acc[oo][r]);
                    acc[oo][r] = fmaf(w[oo].w, a[r].w, acc[oo][r]);
                }
        }
        #pragma unroll
        for (int oo = 0; oo < 4; ++oo)
            #pragma unroll
            for (int r = 0; r < 4; ++r) acc[oo][r] = qsum8(acc[oo][r]);
        if (q == 0) {
            #pragma unroll
            for (int oo = 0; oo < 4; ++oo) {
                const int o = g * 4 + oo;
                const float bias = b1[o];
                #pragma unroll
                for (int r = 0; r < 4; ++r) h2s[r][o] = elu1(acc[oo][r] + bias);
            }
        }
    }
    __syncthreads();

    // ---- phase D: ts[r][j] = h2s[r] . W2[j,:]  (j < 126) ----
    // group g owns j = 2g, 2g+1 (g==63 idle); lane q covers h = q*4 + jj*32
    {
        float acc[2][4];
        #pragma unroll
        for (int oo = 0; oo < 2; ++oo)
            #pragma unroll
            for (int r = 0; r < 4; ++r) acc[oo][r] = 0.0f;

        if (g < 63) {
            const float* w2p = W2 + (g * 2) * H2_;
            #pragma unroll
            for (int jj = 0; jj < 8; ++jj) {
                const int h = q * 4 + jj * 32;
                float4 w[2], a[4];
                #pragma unroll
                for (int oo = 0; oo < 2; ++oo)
                    w[oo] = *reinterpret_cast<const float4*>(w2p + oo * H2_ + h);
                #pragma unroll
                for (int r = 0; r < 4; ++r)
                    a[r] = *reinterpret_cast<const float4*>(&h2s[r][h]);
                #pragma unroll
                for (int oo = 0; oo < 2; ++oo)
                    #pragma unroll
                    for (int r = 0; r < 4; ++r) {
                        acc[oo][r] = fmaf(w[oo].x, a[r].x, acc[oo][r]);
                        acc[oo][r] = fmaf(w[oo].y, a[r].y, acc[oo][r]);
                        acc[oo][r] = fmaf(w[oo].z, a[r].z, acc[oo][r]);
                        acc[oo][r] = fmaf(w[oo].w, a[r].w, acc[oo][r]);
                    }
            }
        }
        #pragma unroll
        for (int oo = 0; oo < 2; ++oo)
            #pragma unroll
            for (int r = 0; r < 4; ++r) acc[oo][r] = qsum8(acc[oo][r]);
        if (q == 0 && g < 63) {
            #pragma unroll
            for (int oo = 0; oo < 2; ++oo) {
                const int j = g * 2 + oo;
                #pragma unroll
                for (int r = 0; r < 4; ++r) ts[r][j] = acc[oo][r];
            }
        }
    }
    __syncthreads();

    // ---- phase E: out[b,o] = sum_k (j<126 ? ts[r][j] + b2[j] : 0) ----
    for (int n = tid; n < RPB * NOUT_; n += TPB) {
        const int r = n / NOUT_;
        const int o = n - r * NOUT_;
        const int base = (row0 + r) * (NOUT_ * K_) + o * K_;
        float v = 0.0f;
        #pragma unroll
        for (int k = 0; k < K_; ++k) {
            const int j = oidx[base + k];
            if (j < NOUT_) v += ts[r][j] + b2[j];
        }
        out[(row0 + r) * NOUT_ + o] = v;
    }
}

extern "C" void kernel_launch(void* const* d_in, const int* in_sizes, int n_in,
                              void* d_out, int out_size, void* d_ws, size_t ws_size,
                              hipStream_t stream) {
    const float* x   = (const float*)d_in[0];
    const float* W0  = (const float*)d_in[1];
    const float* b0  = (const float*)d_in[2];
    const float* W1  = (const float*)d_in[3];
    const float* b1  = (const float*)d_in[4];
    const float* W2  = (const float*)d_in[5];
    const float* b2  = (const float*)d_in[6];
    const int*  iidx = (const int*)d_in[7];
    const int*  oidx = (const int*)d_in[8];
    float* out = (float*)d_out;

    bim_fused<<<B_ / RPB, TPB, 0, stream>>>(x, W0, b0, W1, b1, W2, b2, iidx, oidx, out);
}

// Round 3
// 18.152 us; speedup vs baseline: 2.3306x; 1.1110x over previous
//
#include <hip/hip_runtime.h>

#define B_    1024
#define NIN_  126
#define NOUT_ 126
#define K_    3
#define H1_   256
#define H2_   256
#define RPB   4      // batch rows per block
#define TPB   1024   // 16 waves -> 4 waves/SIMD at 1 block/CU

__device__ __forceinline__ float elu1(float v) { return v > 0.0f ? v : expm1f(v); }

// butterfly sum over 8 consecutive lanes (q = lane&7); result in all 8 lanes
__device__ __forceinline__ float qsum8(float v) {
    v += __shfl_xor(v, 1);
    v += __shfl_xor(v, 2);
    v += __shfl_xor(v, 4);
    return v;
}

// static 8-way select: pick acc[i] for i==q without runtime array indexing
__device__ __forceinline__ float sel8(int q, float a0, float a1, float a2, float a3,
                                      float a4, float a5, float a6, float a7) {
    float v = a0;
    v = (q == 1) ? a1 : v;  v = (q == 2) ? a2 : v;  v = (q == 3) ? a3 : v;
    v = (q == 4) ? a4 : v;  v = (q == 5) ? a5 : v;  v = (q == 6) ? a6 : v;
    v = (q == 7) ? a7 : v;
    return v;
}

__global__ __launch_bounds__(TPB, 4) void bim_fused(
    const float* __restrict__ x,  const float* __restrict__ W0,
    const float* __restrict__ b0, const float* __restrict__ W1,
    const float* __restrict__ b1, const float* __restrict__ W2,
    const float* __restrict__ b2, const int*  __restrict__ iidx,
    const int*  __restrict__ oidx, float* __restrict__ out)
{
    __shared__ float xe [RPB][128];   // scattered x (cols 126/127 stay 0)
    __shared__ float h1s[RPB][H1_];
    __shared__ float h2s[RPB][H2_];
    __shared__ float ts [RPB][128];   // t[r][j] = h2[r] . W2[j,:]

    const int tid  = threadIdx.x;
    const int row0 = blockIdx.x * RPB;
    const int q    = tid & 7;   // k-split lane within group
    const int g    = tid >> 3;  // group id 0..127

    // ---- phase A: zero xe, scatter-accumulate x by batch_in_index ----
    for (int n = tid; n < RPB * 128; n += TPB) (&xe[0][0])[n] = 0.0f;
    __syncthreads();

    for (int n = tid; n < RPB * NIN_ * K_; n += TPB) {
        const int r = n / (NIN_ * K_);
        const int m = n - r * (NIN_ * K_);
        const int i = m / K_;
        const int j = iidx[(row0 + r) * (NIN_ * K_) + m];
        if (j < NIN_) atomicAdd(&xe[r][j], x[(row0 + r) * NIN_ + i]);
    }
    __syncthreads();

    // ---- phase B: h1 = elu(xe @ W0^T + b0) ----
    // group g owns outputs o = 2g, 2g+1; lane q covers j = q*2 + jj*16 (float2)
    {
        float acc[2][4];
        #pragma unroll
        for (int oo = 0; oo < 2; ++oo)
            #pragma unroll
            for (int r = 0; r < 4; ++r) acc[oo][r] = 0.0f;

        const float* w0p = W0 + (g * 2) * NIN_;
        #pragma unroll 2
        for (int jj = 0; jj < 8; ++jj) {
            const int j = q * 2 + jj * 16;
            const bool ok = (j < NIN_);             // j==126 is the zero pad
            float2 w0 = ok ? *reinterpret_cast<const float2*>(w0p + j)
                           : make_float2(0.f, 0.f);
            float2 w1 = ok ? *reinterpret_cast<const float2*>(w0p + NIN_ + j)
                           : make_float2(0.f, 0.f);
            float2 a[4];
            #pragma unroll
            for (int r = 0; r < 4; ++r)
                a[r] = *reinterpret_cast<const float2*>(&xe[r][j]);  // cols 126/127 are 0
            #pragma unroll
            for (int r = 0; r < 4; ++r) {
                acc[0][r] = fmaf(w0.x, a[r].x, acc[0][r]);
                acc[0][r] = fmaf(w0.y, a[r].y, acc[0][r]);
                acc[1][r] = fmaf(w1.x, a[r].x, acc[1][r]);
                acc[1][r] = fmaf(w1.y, a[r].y, acc[1][r]);
            }
        }
        #pragma unroll
        for (int oo = 0; oo < 2; ++oo)
            #pragma unroll
            for (int r = 0; r < 4; ++r) acc[oo][r] = qsum8(acc[oo][r]);
        // lane q handles (oo = q>>2, r = q&3): all lanes do one elu + one write
        const int oo = q >> 2, rr = q & 3;
        const int o  = g * 2 + oo;
        const float v = sel8(q, acc[0][0], acc[0][1], acc[0][2], acc[0][3],
                                acc[1][0], acc[1][1], acc[1][2], acc[1][3]);
        const float hv = elu1(v + b0[o]);
        if (rr == 0) h1s[0][o] = hv;
        if (rr == 1) h1s[1][o] = hv;
        if (rr == 2) h1s[2][o] = hv;
        if (rr == 3) h1s[3][o] = hv;
    }
    __syncthreads();

    // ---- phase C: h2 = elu(h1 @ W1^T + b1) ----
    // group g owns o = 2g, 2g+1; lane q covers j = q*4 + jj*32 (float4)
    {
        float acc[2][4];
        #pragma unroll
        for (int oo = 0; oo < 2; ++oo)
            #pragma unroll
            for (int r = 0; r < 4; ++r) acc[oo][r] = 0.0f;

        const float* w1p = W1 + (g * 2) * H1_;
        #pragma unroll 2
        for (int jj = 0; jj < 8; ++jj) {
            const int j = q * 4 + jj * 32;
            const float4 w0 = *reinterpret_cast<const float4*>(w1p + j);
            const float4 w1 = *reinterpret_cast<const float4*>(w1p + H1_ + j);
            float4 a[4];
            #pragma unroll
            for (int r = 0; r < 4; ++r)
                a[r] = *reinterpret_cast<const float4*>(&h1s[r][j]);
            #pragma unroll
            for (int r = 0; r < 4; ++r) {
                acc[0][r] = fmaf(w0.x, a[r].x, acc[0][r]);
                acc[0][r] = fmaf(w0.y, a[r].y, acc[0][r]);
                acc[0][r] = fmaf(w0.z, a[r].z, acc[0][r]);
                acc[0][r] = fmaf(w0.w, a[r].w, acc[0][r]);
                acc[1][r] = fmaf(w1.x, a[r].x, acc[1][r]);
                acc[1][r] = fmaf(w1.y, a[r].y, acc[1][r]);
                acc[1][r] = fmaf(w1.z, a[r].z, acc[1][r]);
                acc[1][r] = fmaf(w1.w, a[r].w, acc[1][r]);
            }
        }
        #pragma unroll
        for (int oo = 0; oo < 2; ++oo)
            #pragma unroll
            for (int r = 0; r < 4; ++r) acc[oo][r] = qsum8(acc[oo][r]);
        const int oo = q >> 2, rr = q & 3;
        const int o  = g * 2 + oo;
        const float v = sel8(q, acc[0][0], acc[0][1], acc[0][2], acc[0][3],
                                acc[1][0], acc[1][1], acc[1][2], acc[1][3]);
        const float hv = elu1(v + b1[o]);
        if (rr == 0) h2s[0][o] = hv;
        if (rr == 1) h2s[1][o] = hv;
        if (rr == 2) h2s[2][o] = hv;
        if (rr == 3) h2s[3][o] = hv;
    }
    __syncthreads();

    // ---- phase D: ts[r][j] = h2s[r] . W2[j,:]  (j < 126) ----
    // group g owns j = g (g<126); lane q covers h = q*4 + jj*32
    if (g < NOUT_) {
        float acc[4];
        #pragma unroll
        for (int r = 0; r < 4; ++r) acc[r] = 0.0f;

        const float* w2p = W2 + g * H2_;
        #pragma unroll 2
        for (int jj = 0; jj < 8; ++jj) {
            const int h = q * 4 + jj * 32;
            const float4 w = *reinterpret_cast<const float4*>(w2p + h);
            float4 a[4];
            #pragma unroll
            for (int r = 0; r < 4; ++r)
                a[r] = *reinterpret_cast<const float4*>(&h2s[r][h]);
            #pragma unroll
            for (int r = 0; r < 4; ++r) {
                acc[r] = fmaf(w.x, a[r].x, acc[r]);
                acc[r] = fmaf(w.y, a[r].y, acc[r]);
                acc[r] = fmaf(w.z, a[r].z, acc[r]);
                acc[r] = fmaf(w.w, a[r].w, acc[r]);
            }
        }
        #pragma unroll
        for (int r = 0; r < 4; ++r) acc[r] = qsum8(acc[r]);
        const float v = sel8(q, acc[0], acc[1], acc[2], acc[3],
                                acc[0], acc[1], acc[2], acc[3]);
        if (q == 0) ts[0][g] = v;
        if (q == 1) ts[1][g] = v;
        if (q == 2) ts[2][g] = v;
        if (q == 3) ts[3][g] = v;
    }
    __syncthreads();

    // ---- phase E: out[b,o] = sum_k (j<126 ? ts[r][j] + b2[j] : 0) ----
    for (int n = tid; n < RPB * NOUT_; n += TPB) {
        const int r = n / NOUT_;
        const int o = n - r * NOUT_;
        const int base = (row0 + r) * (NOUT_ * K_) + o * K_;
        float v = 0.0f;
        #pragma unroll
        for (int k = 0; k < K_; ++k) {
            const int j = oidx[base + k];
            if (j < NOUT_) v += ts[r][j] + b2[j];
        }
        out[(row0 + r) * NOUT_ + o] = v;
    }
}

extern "C" void kernel_launch(void* const* d_in, const int* in_sizes, int n_in,
                              void* d_out, int out_size, void* d_ws, size_t ws_size,
                              hipStream_t stream) {
    const float* x   = (const float*)d_in[0];
    const float* W0  = (const float*)d_in[1];
    const float* b0  = (const float*)d_in[2];
    const float* W1  = (const float*)d_in[3];
    const float* b1  = (const float*)d_in[4];
    const float* W2  = (const float*)d_in[5];
    const float* b2  = (const float*)d_in[6];
    const int*  iidx = (const int*)d_in[7];
    const int*  oidx = (const int*)d_in[8];
    float* out = (float*)d_out;

    bim_fused<<<B_ / RPB, TPB, 0, stream>>>(x, W0, b0, W1, b1, W2, b2, iidx, oidx, out);
}

// Round 4
// 17.436 us; speedup vs baseline: 2.4264x; 1.0411x over previous
//
#include <hip/hip_runtime.h>

#define B_    1024
#define NIN_  126
#define NOUT_ 126
#define K_    3
#define H1_   256
#define H2_   256
#define RPB   4
#define TPB   1024   // 16 waves, 1 block/CU, grid = 256

__device__ __forceinline__ float elu1(float v) { return v > 0.0f ? v : expm1f(v); }

// butterfly sum over 8 consecutive lanes; result in all 8 lanes
__device__ __forceinline__ float qsum8(float v) {
    v += __shfl_xor(v, 1);
    v += __shfl_xor(v, 2);
    v += __shfl_xor(v, 4);
    return v;
}

// static 8-way select without runtime array indexing
__device__ __forceinline__ float sel8(int q, float a0, float a1, float a2, float a3,
                                      float a4, float a5, float a6, float a7) {
    float v = a0;
    v = (q == 1) ? a1 : v;  v = (q == 2) ? a2 : v;  v = (q == 3) ? a3 : v;
    v = (q == 4) ? a4 : v;  v = (q == 5) ? a5 : v;  v = (q == 6) ? a6 : v;
    v = (q == 7) ? a7 : v;
    return v;
}

__global__ __launch_bounds__(TPB) void bim_fused(
    const float* __restrict__ x,  const float* __restrict__ W0,
    const float* __restrict__ b0, const float* __restrict__ W1,
    const float* __restrict__ b1, const float* __restrict__ W2,
    const float* __restrict__ b2, const int*  __restrict__ iidx,
    const int*  __restrict__ oidx, float* __restrict__ out)
{
    __shared__ float xe [RPB][128];   // scattered x; cols 126/127 stay 0
    __shared__ float h1s[RPB][H1_];
    __shared__ float h2s[RPB][H2_];
    __shared__ float ts [RPB][128];   // cols 126/127 zeroed in phase D

    const int tid  = threadIdx.x;
    const int row0 = blockIdx.x * RPB;
    const int q    = tid & 7;   // k-split lane within 8-lane group
    const int g    = tid >> 3;  // group id 0..127

    // ================= EARLY ISSUE (all drain at first barrier) =============
    // --- phase-A scatter operands (2 items/thread, item 2 clamped) ---
    int ar0, aj0; float ax0;
    int ar1, aj1; float ax1;
    {
        const int n0 = tid;                      // < 1512 always
        ar0 = n0 / (NIN_ * K_);
        const int m0 = n0 - ar0 * (NIN_ * K_);
        aj0 = iidx[(row0 + ar0) * (NIN_ * K_) + m0];
        ax0 = x[(row0 + ar0) * NIN_ + m0 / K_];

        const int n1  = tid + TPB;
        const int n1c = n1 < RPB * NIN_ * K_ ? n1 : RPB * NIN_ * K_ - 1;
        ar1 = n1c / (NIN_ * K_);
        const int m1 = n1c - ar1 * (NIN_ * K_);
        aj1 = iidx[(row0 + ar1) * (NIN_ * K_) + m1];
        ax1 = x[(row0 + ar1) * NIN_ + m1 / K_];
    }

    // --- phase-E output indices (1 output element/thread for tid<504) ---
    int ej0, ej1, ej2;
    {
        const int t = tid < RPB * NOUT_ ? tid : 0;
        const int r = t / NOUT_, o = t - r * NOUT_;
        const int base = (row0 + r) * (NOUT_ * K_) + o * K_;
        ej0 = oidx[base + 0];
        ej1 = oidx[base + 1];
        ej2 = oidx[base + 2];
    }

    // --- phase-B weights: W0 rows 2g, 2g+1; branch-free clamped addresses ---
    float2 wb0[8], wb1[8];
    {
        const float* w0p = W0 + (g * 2) * NIN_;
        #pragma unroll
        for (int jj = 0; jj < 8; ++jj) {
            const int j  = q * 2 + jj * 16;
            const int jc = j > NIN_ - 2 ? NIN_ - 2 : j;  // only q==7,jj==7 clamps
            wb0[jj] = *reinterpret_cast<const float2*>(w0p + jc);
            wb1[jj] = *reinterpret_cast<const float2*>(w0p + NIN_ + jc);
        }
    }
    const float2 b0v = *reinterpret_cast<const float2*>(b0 + g * 2);
    const float2 b1v = *reinterpret_cast<const float2*>(b1 + g * 2);

    // ================= phase A: zero xe, barrier (drains prefetch), scatter ==
    for (int n = tid; n < RPB * 128; n += TPB) (&xe[0][0])[n] = 0.0f;
    __syncthreads();   // single ~900cy fill window for ALL top prefetches

    if (aj0 < NIN_) atomicAdd(&xe[ar0][aj0], ax0);
    if (tid < RPB * NIN_ * K_ - TPB && aj1 < NIN_) atomicAdd(&xe[ar1][aj1], ax1);
    __syncthreads();

    // ---- issue phase-C weights now: covered by B compute + reduce ----
    float4 wc0[8], wc1[8];
    {
        const float* w1p = W1 + (g * 2) * H1_;
        #pragma unroll
        for (int jj = 0; jj < 8; ++jj) {
            const int j = q * 4 + jj * 32;
            wc0[jj] = *reinterpret_cast<const float4*>(w1p + j);
            wc1[jj] = *reinterpret_cast<const float4*>(w1p + H1_ + j);
        }
    }

    // ================= phase B: h1 = elu(xe @ W0^T + b0) ====================
    {
        float acc0[RPB] = {0.f, 0.f, 0.f, 0.f};
        float acc1[RPB] = {0.f, 0.f, 0.f, 0.f};
        #pragma unroll
        for (int jj = 0; jj < 8; ++jj) {
            const int j = q * 2 + jj * 16;       // unclamped: xe pad cols are 0
            #pragma unroll
            for (int r = 0; r < RPB; ++r) {
                const float2 a = *reinterpret_cast<const float2*>(&xe[r][j]);
                acc0[r] = fmaf(wb0[jj].x, a.x, acc0[r]);
                acc0[r] = fmaf(wb0[jj].y, a.y, acc0[r]);
                acc1[r] = fmaf(wb1[jj].x, a.x, acc1[r]);
                acc1[r] = fmaf(wb1[jj].y, a.y, acc1[r]);
            }
        }
        #pragma unroll
        for (int r = 0; r < RPB; ++r) { acc0[r] = qsum8(acc0[r]); acc1[r] = qsum8(acc1[r]); }
        const int oo = q >> 2, rr = q & 3;
        const float v  = sel8(q, acc0[0], acc0[1], acc0[2], acc0[3],
                                 acc1[0], acc1[1], acc1[2], acc1[3]);
        const float bias = oo ? b0v.y : b0v.x;
        h1s[rr][g * 2 + oo] = elu1(v + bias);
    }
    __syncthreads();   // drains wc (mostly covered)

    // ================= phase C: h2 = elu(h1 @ W1^T + b1) ====================
    float4 wd[8];      // phase-D weights, issued right after C's FMAs
    {
        float acc0[RPB] = {0.f, 0.f, 0.f, 0.f};
        float acc1[RPB] = {0.f, 0.f, 0.f, 0.f};
        #pragma unroll
        for (int jj = 0; jj < 8; ++jj) {
            const int j = q * 4 + jj * 32;
            #pragma unroll
            for (int r = 0; r < RPB; ++r) {
                const float4 a = *reinterpret_cast<const float4*>(&h1s[r][j]);
                acc0[r] = fmaf(wc0[jj].x, a.x, acc0[r]);
                acc0[r] = fmaf(wc0[jj].y, a.y, acc0[r]);
                acc0[r] = fmaf(wc0[jj].z, a.z, acc0[r]);
                acc0[r] = fmaf(wc0[jj].w, a.w, acc0[r]);
                acc1[r] = fmaf(wc1[jj].x, a.x, acc1[r]);
                acc1[r] = fmaf(wc1[jj].y, a.y, acc1[r]);
                acc1[r] = fmaf(wc1[jj].z, a.z, acc1[r]);
                acc1[r] = fmaf(wc1[jj].w, a.w, acc1[r]);
            }
        }
        // ---- issue phase-D weights (W2 row g, clamped for g>=126) ----
        {
            const float* w2p = W2 + (g < NOUT_ ? g : 0) * H2_;
            #pragma unroll
            for (int jj = 0; jj < 8; ++jj)
                wd[jj] = *reinterpret_cast<const float4*>(w2p + q * 4 + jj * 32);
        }
        #pragma unroll
        for (int r = 0; r < RPB; ++r) { acc0[r] = qsum8(acc0[r]); acc1[r] = qsum8(acc1[r]); }
        const int oo = q >> 2, rr = q & 3;
        const float v  = sel8(q, acc0[0], acc0[1], acc0[2], acc0[3],
                                 acc1[0], acc1[1], acc1[2], acc1[3]);
        const float bias = oo ? b1v.y : b1v.x;
        h2s[rr][g * 2 + oo] = elu1(v + bias);
    }
    __syncthreads();   // drains wd (mostly covered)

    // ================= phase D: ts[r][g] = h2s[r] . W2[g,:] =================
    if (g < NOUT_) {
        float acc[RPB] = {0.f, 0.f, 0.f, 0.f};
        #pragma unroll
        for (int jj = 0; jj < 8; ++jj) {
            const int h = q * 4 + jj * 32;
            #pragma unroll
            for (int r = 0; r < RPB; ++r) {
                const float4 a = *reinterpret_cast<const float4*>(&h2s[r][h]);
                acc[r] = fmaf(wd[jj].x, a.x, acc[r]);
                acc[r] = fmaf(wd[jj].y, a.y, acc[r]);
                acc[r] = fmaf(wd[jj].z, a.z, acc[r]);
                acc[r] = fmaf(wd[jj].w, a.w, acc[r]);
            }
        }
        #pragma unroll
        for (int r = 0; r < RPB; ++r) acc[r] = qsum8(acc[r]);
        if (q < 4) {
            const float v = sel8(q, acc[0], acc[1], acc[2], acc[3],
                                    acc[0], acc[1], acc[2], acc[3]);
            ts[q][g] = v;
        }
    } else {
        if (q < 4) ts[q][g] = 0.0f;   // zero pad cols 126,127
    }
    __syncthreads();

    // ================= phase E: gather + bias, store out ====================
    if (tid < RPB * NOUT_) {
        const int r = tid / NOUT_, o = tid - r * NOUT_;
        float v = ts[r][ej0] + ts[r][ej1] + ts[r][ej2];   // ts[r][126] == 0
        v += (ej0 < NOUT_) ? b2[ej0] : 0.0f;
        v += (ej1 < NOUT_) ? b2[ej1] : 0.0f;
        v += (ej2 < NOUT_) ? b2[ej2] : 0.0f;
        out[(row0 + r) * NOUT_ + o] = v;
    }
}

extern "C" void kernel_launch(void* const* d_in, const int* in_sizes, int n_in,
                              void* d_out, int out_size, void* d_ws, size_t ws_size,
                              hipStream_t stream) {
    const float* x   = (const float*)d_in[0];
    const float* W0  = (const float*)d_in[1];
    const float* b0  = (const float*)d_in[2];
    const float* W1  = (const float*)d_in[3];
    const float* b1  = (const float*)d_in[4];
    const float* W2  = (const float*)d_in[5];
    const float* b2  = (const float*)d_in[6];
    const int*  iidx = (const int*)d_in[7];
    const int*  oidx = (const int*)d_in[8];
    float* out = (float*)d_out;

    bim_fused<<<B_ / RPB, TPB, 0, stream>>>(x, W0, b0, W1, b1, W2, b2, iidx, oidx, out);
}

// Round 5
// 16.335 us; speedup vs baseline: 2.5899x; 1.0674x over previous
//
#include <hip/hip_runtime.h>

#define B_    1024
#define NIN_  126
#define NOUT_ 126
#define K_    3
#define H1_   256
#define H2_   256
#define RPB   4
#define TPB   512    // 8 waves, 1 block/CU, grid = 256

__device__ __forceinline__ float elu1(float v) { return v > 0.0f ? v : expm1f(v); }

// DPP quad_perm add (VALU pipe, no LDS traffic)
template<int CTRL>
__device__ __forceinline__ float dpp_add(float v) {
    int s = __builtin_amdgcn_update_dpp(0, __float_as_int(v), CTRL, 0xF, 0xF, true);
    return v + __int_as_float(s);
}
// sum over 8 consecutive lanes: xor1,xor2 on VALU (DPP), xor4 via one ds_swizzle
__device__ __forceinline__ float qsum8(float v) {
    v = dpp_add<0xB1>(v);                                    // + lane^1  [1,0,3,2]
    v = dpp_add<0x4E>(v);                                    // + lane^2  [2,3,0,1]
    int s = __builtin_amdgcn_ds_swizzle(__float_as_int(v), 0x101F); // lane^4
    return v + __int_as_float(s);
}

// barrier that drains ONLY LDS ops; global loads stay in flight (vmcnt untouched)
__device__ __forceinline__ void barrier_lds() {
    asm volatile("s_waitcnt lgkmcnt(0)\n\ts_barrier" ::: "memory");
}

__global__ __launch_bounds__(TPB, 2) void bim_fused(
    const float* __restrict__ x,  const float* __restrict__ W0,
    const float* __restrict__ b0, const float* __restrict__ W1,
    const float* __restrict__ b1, const float* __restrict__ W2,
    const float* __restrict__ b2, const int*  __restrict__ iidx,
    const int*  __restrict__ oidx, float* __restrict__ out)
{
    __shared__ float xe [RPB][128];   // scattered x; cols 126/127 stay 0
    __shared__ float h1s[RPB][H1_];
    __shared__ float h2s[RPB][H2_];
    __shared__ float ts [RPB][128];   // += b2 folded in; cols 126/127 zeroed

    const int tid  = threadIdx.x;
    const int row0 = blockIdx.x * RPB;
    const int q    = tid & 7;    // k-split lane
    const int g    = tid >> 3;   // group 0..63

    // ======== top prefetch (issue order matters: A ops first) ========
    int aj0, aj1, aj2, ar0, ar1, ar2; float ax0, ax1, ax2;
    {
        const int n0 = tid;
        ar0 = n0 / (NIN_ * K_); const int m0 = n0 - ar0 * (NIN_ * K_);
        aj0 = iidx[(row0 + ar0) * (NIN_ * K_) + m0];
        ax0 = x[(row0 + ar0) * NIN_ + m0 / K_];
        const int n1 = tid + TPB;                 // always < 1512
        ar1 = n1 / (NIN_ * K_); const int m1 = n1 - ar1 * (NIN_ * K_);
        aj1 = iidx[(row0 + ar1) * (NIN_ * K_) + m1];
        ax1 = x[(row0 + ar1) * NIN_ + m1 / K_];
        const int n2 = tid + 2 * TPB;
        const int n2c = n2 < RPB * NIN_ * K_ ? n2 : 0;
        ar2 = n2c / (NIN_ * K_); const int m2 = n2c - ar2 * (NIN_ * K_);
        aj2 = iidx[(row0 + ar2) * (NIN_ * K_) + m2];
        ax2 = x[(row0 + ar2) * NIN_ + m2 / K_];
        if (n2 >= RPB * NIN_ * K_) aj2 = NIN_;    // skip marker
    }
    int ej0, ej1, ej2;
    {
        const int t = tid < RPB * NOUT_ ? tid : 0;
        const int r = t / NOUT_, o = t - r * NOUT_;
        const int base = (row0 + r) * (NOUT_ * K_) + o * K_;
        ej0 = oidx[base]; ej1 = oidx[base + 1]; ej2 = oidx[base + 2];
    }
    // phase-B weights: W0 rows 4g..4g+3, lane q covers j = q*4 + jj*32 (jj<4)
    float2 wbA[4][4], wbB[4][4];
    #pragma unroll
    for (int oo = 0; oo < 4; ++oo) {
        const float* wp = W0 + (g * 4 + oo) * NIN_;
        #pragma unroll
        for (int jj = 0; jj < 4; ++jj) {
            const int j  = q * 4 + jj * 32;
            const int j2 = (j + 2 > NIN_ - 2) ? (NIN_ - 2) : (j + 2); // clamp; xe pad=0 kills garbage
            wbA[jj][oo] = *reinterpret_cast<const float2*>(wp + j);
            wbB[jj][oo] = *reinterpret_cast<const float2*>(wp + j2);
        }
    }
    const float4 b0v = *reinterpret_cast<const float4*>(b0 + g * 4);
    const float4 b1v = *reinterpret_cast<const float4*>(b1 + g * 4);
    const int   gD   = (g < 63) ? g : 0;
    const float2 b2v = *reinterpret_cast<const float2*>(b2 + gD * 2);

    // ======== phase A: zero xe, LDS-barrier (weights stay in flight), scatter
    (&xe[0][0])[tid] = 0.0f;
    barrier_lds();
    if (aj0 < NIN_) atomicAdd(&xe[ar0][aj0], ax0);
    if (aj1 < NIN_) atomicAdd(&xe[ar1][aj1], ax1);
    if (aj2 < NIN_) atomicAdd(&xe[ar2][aj2], ax2);

    // issue phase-C weights now: covered by scatter + all of phase B
    float4 wc[8][4];
    #pragma unroll
    for (int oo = 0; oo < 4; ++oo) {
        const float* wp = W1 + (g * 4 + oo) * H1_;
        #pragma unroll
        for (int jj = 0; jj < 8; ++jj)
            wc[jj][oo] = *reinterpret_cast<const float4*>(wp + q * 4 + jj * 32);
    }
    barrier_lds();

    // ======== phase B: h1 = elu(xe @ W0^T + b0), 4 outputs/group ========
    {
        float acc[4][4] = {};  // [oo][r]
        #pragma unroll
        for (int jj = 0; jj < 4; ++jj) {
            const int j = q * 4 + jj * 32;
            #pragma unroll
            for (int r = 0; r < RPB; ++r) {
                const float4 a = *reinterpret_cast<const float4*>(&xe[r][j]);
                #pragma unroll
                for (int oo = 0; oo < 4; ++oo) {
                    acc[oo][r] = fmaf(wbA[jj][oo].x, a.x, acc[oo][r]);
                    acc[oo][r] = fmaf(wbA[jj][oo].y, a.y, acc[oo][r]);
                    acc[oo][r] = fmaf(wbB[jj][oo].x, a.z, acc[oo][r]);
                    acc[oo][r] = fmaf(wbB[jj][oo].y, a.w, acc[oo][r]);
                }
            }
        }
        #pragma unroll
        for (int oo = 0; oo < 4; ++oo)
            #pragma unroll
            for (int r = 0; r < RPB; ++r) acc[oo][r] = qsum8(acc[oo][r]);
        // lane q writes flat accs 2q, 2q+1  (flat = oo*4 + r)
        float v0 = acc[0][0], v1 = acc[0][1];
        #pragma unroll
        for (int i = 1; i < 8; ++i) {
            v0 = (q == i) ? acc[(2 * i) >> 2][(2 * i) & 3]         : v0;
            v1 = (q == i) ? acc[(2 * i + 1) >> 2][(2 * i + 1) & 3] : v1;
        }
        const int oo = q >> 1, r0 = (q & 1) * 2;
        const float bias = (oo == 0) ? b0v.x : (oo == 1) ? b0v.y : (oo == 2) ? b0v.z : b0v.w;
        const int o = g * 4 + oo;
        h1s[r0][o]     = elu1(v0 + bias);
        h1s[r0 + 1][o] = elu1(v1 + bias);
    }
    barrier_lds();

    // ======== phase C: h2 = elu(h1 @ W1^T + b1), 4 outputs/group ========
    float4 wd[8][2];
    {
        float acc[4][4] = {};
        #pragma unroll
        for (int jj = 0; jj < 8; ++jj) {
            const int j = q * 4 + jj * 32;
            #pragma unroll
            for (int r = 0; r < RPB; ++r) {
                const float4 a = *reinterpret_cast<const float4*>(&h1s[r][j]);
                #pragma unroll
                for (int oo = 0; oo < 4; ++oo) {
                    acc[oo][r] = fmaf(wc[jj][oo].x, a.x, acc[oo][r]);
                    acc[oo][r] = fmaf(wc[jj][oo].y, a.y, acc[oo][r]);
                    acc[oo][r] = fmaf(wc[jj][oo].z, a.z, acc[oo][r]);
                    acc[oo][r] = fmaf(wc[jj][oo].w, a.w, acc[oo][r]);
                }
            }
        }
        // issue phase-D weights (W2 rows 2gD, 2gD+1): covered by C reduce
        #pragma unroll
        for (int oo = 0; oo < 2; ++oo) {
            const float* wp = W2 + (gD * 2 + oo) * H2_;
            #pragma unroll
            for (int jj = 0; jj < 8; ++jj)
                wd[jj][oo] = *reinterpret_cast<const float4*>(wp + q * 4 + jj * 32);
        }
        #pragma unroll
        for (int oo = 0; oo < 4; ++oo)
            #pragma unroll
            for (int r = 0; r < RPB; ++r) acc[oo][r] = qsum8(acc[oo][r]);
        float v0 = acc[0][0], v1 = acc[0][1];
        #pragma unroll
        for (int i = 1; i < 8; ++i) {
            v0 = (q == i) ? acc[(2 * i) >> 2][(2 * i) & 3]         : v0;
            v1 = (q == i) ? acc[(2 * i + 1) >> 2][(2 * i + 1) & 3] : v1;
        }
        const int oo = q >> 1, r0 = (q & 1) * 2;
        const float bias = (oo == 0) ? b1v.x : (oo == 1) ? b1v.y : (oo == 2) ? b1v.z : b1v.w;
        const int o = g * 4 + oo;
        h2s[r0][o]     = elu1(v0 + bias);
        h2s[r0 + 1][o] = elu1(v1 + bias);
    }
    barrier_lds();

    // ======== phase D: ts[r][j] = h2s[r].W2[j,:] + b2[j], 2 rows/group ====
    {
        float acc[2][4] = {};  // [oo][r]
        #pragma unroll
        for (int jj = 0; jj < 8; ++jj) {
            const int j = q * 4 + jj * 32;
            #pragma unroll
            for (int r = 0; r < RPB; ++r) {
                const float4 a = *reinterpret_cast<const float4*>(&h2s[r][j]);
                #pragma unroll
                for (int oo = 0; oo < 2; ++oo) {
                    acc[oo][r] = fmaf(wd[jj][oo].x, a.x, acc[oo][r]);
                    acc[oo][r] = fmaf(wd[jj][oo].y, a.y, acc[oo][r]);
                    acc[oo][r] = fmaf(wd[jj][oo].z, a.z, acc[oo][r]);
                    acc[oo][r] = fmaf(wd[jj][oo].w, a.w, acc[oo][r]);
                }
            }
        }
        #pragma unroll
        for (int oo = 0; oo < 2; ++oo)
            #pragma unroll
            for (int r = 0; r < RPB; ++r) acc[oo][r] = qsum8(acc[oo][r]);
        // lane q writes flat acc q (flat = oo*4 + r)
        float v = acc[0][0];
        #pragma unroll
        for (int i = 1; i < 8; ++i) v = (q == i) ? acc[i >> 2][i & 3] : v;
        const int oo = q >> 2, rr = q & 3;
        if (g < 63) ts[rr][g * 2 + oo] = v + (oo ? b2v.y : b2v.x);
        else        ts[rr][126 + oo]   = 0.0f;   // zero pads (8 lanes cover [4][2])
    }
    barrier_lds();

    // ======== phase E: out[b,o] = sum_k ts[r][ej_k]  (b2 already folded) ===
    if (tid < RPB * NOUT_) {
        const int r = tid / NOUT_, o = tid - r * NOUT_;
        out[(row0 + r) * NOUT_ + o] = ts[r][ej0] + ts[r][ej1] + ts[r][ej2];
    }
}

extern "C" void kernel_launch(void* const* d_in, const int* in_sizes, int n_in,
                              void* d_out, int out_size, void* d_ws, size_t ws_size,
                              hipStream_t stream) {
    const float* x   = (const float*)d_in[0];
    const float* W0  = (const float*)d_in[1];
    const float* b0  = (const float*)d_in[2];
    const float* W1  = (const float*)d_in[3];
    const float* b1  = (const float*)d_in[4];
    const float* W2  = (const float*)d_in[5];
    const float* b2  = (const float*)d_in[6];
    const int*  iidx = (const int*)d_in[7];
    const int*  oidx = (const int*)d_in[8];
    float* out = (float*)d_out;

    bim_fused<<<B_ / RPB, TPB, 0, stream>>>(x, W0, b0, W1, b1, W2, b2, iidx, oidx, out);
}

// Round 6
// 15.831 us; speedup vs baseline: 2.6723x; 1.0318x over previous
//
#include <hip/hip_runtime.h>

#define B_    1024
#define NIN_  126
#define NOUT_ 126
#define K_    3
#define H1_   256
#define H2_   256
#define RPB   4
#define TPB   512    // 8 waves, 1 block/CU, grid = 256

__device__ __forceinline__ float elu1(float v) { return v > 0.0f ? v : expm1f(v); }

// DPP quad_perm add (VALU pipe)
template<int CTRL>
__device__ __forceinline__ float dpp_add(float v) {
    int s = __builtin_amdgcn_update_dpp(0, __float_as_int(v), CTRL, 0xF, 0xF, true);
    return v + __int_as_float(s);
}
// sum over 8 consecutive lanes: xor1,xor2 via DPP, xor4 via ds_swizzle
__device__ __forceinline__ float qsum8(float v) {
    v = dpp_add<0xB1>(v);
    v = dpp_add<0x4E>(v);
    int s = __builtin_amdgcn_ds_swizzle(__float_as_int(v), 0x101F);
    return v + __int_as_float(s);
}

// barrier draining only LDS/SMEM ops; global loads stay in flight
__device__ __forceinline__ void barrier_lds() {
    asm volatile("s_waitcnt lgkmcnt(0)\n\ts_barrier" ::: "memory");
}

__global__ __launch_bounds__(TPB) void bim_fused(
    const float* __restrict__ x,  const float* __restrict__ W0,
    const float* __restrict__ b0, const float* __restrict__ W1,
    const float* __restrict__ b1, const float* __restrict__ W2,
    const float* __restrict__ b2, const int*  __restrict__ iidx,
    const int*  __restrict__ oidx, float* __restrict__ out)
{
    __shared__ float xe [RPB][128];   // scattered x; cols 126/127 stay 0
    __shared__ float h1s[RPB][H1_];
    __shared__ float h2s[RPB][H2_];
    __shared__ float ts [RPB][128];   // b2 folded in; cols 126/127 zeroed

    const int tid  = threadIdx.x;
    const int row0 = blockIdx.x * RPB;
    const int q    = tid & 7;    // k-split lane
    const int g    = tid >> 3;   // group 0..63

    // ---- phase-A operands + phase-E indices + biases (small, issue early) --
    int aj0, aj1, aj2, ar0, ar1, ar2; float ax0, ax1, ax2;
    {
        const int n0 = tid;
        ar0 = n0 / (NIN_ * K_); const int m0 = n0 - ar0 * (NIN_ * K_);
        aj0 = iidx[(row0 + ar0) * (NIN_ * K_) + m0];
        ax0 = x[(row0 + ar0) * NIN_ + m0 / K_];
        const int n1 = tid + TPB;                 // < 1512 always
        ar1 = n1 / (NIN_ * K_); const int m1 = n1 - ar1 * (NIN_ * K_);
        aj1 = iidx[(row0 + ar1) * (NIN_ * K_) + m1];
        ax1 = x[(row0 + ar1) * NIN_ + m1 / K_];
        const int n2 = tid + 2 * TPB;
        const int n2c = n2 < RPB * NIN_ * K_ ? n2 : 0;
        ar2 = n2c / (NIN_ * K_); const int m2 = n2c - ar2 * (NIN_ * K_);
        aj2 = iidx[(row0 + ar2) * (NIN_ * K_) + m2];
        ax2 = x[(row0 + ar2) * NIN_ + m2 / K_];
        if (n2 >= RPB * NIN_ * K_) aj2 = NIN_;
    }
    int ej0, ej1, ej2;
    {
        const int t = tid < RPB * NOUT_ ? tid : 0;
        const int r = t / NOUT_, o = t - r * NOUT_;
        const int base = (row0 + r) * (NOUT_ * K_) + o * K_;
        ej0 = oidx[base]; ej1 = oidx[base + 1]; ej2 = oidx[base + 2];
    }
    const float4 b0v = *reinterpret_cast<const float4*>(b0 + g * 4);
    const float4 b1v = *reinterpret_cast<const float4*>(b1 + g * 4);
    const int    gD  = (g < 63) ? g : 0;
    const float2 b2v = *reinterpret_cast<const float2*>(b2 + gD * 2);

    // ---- phase B first-iteration weights (16 regs, in flight over phase A) -
    const float* wb = W0 + (g * 4) * NIN_;
    float2 wA[4], wB[4];
    {
        const int j = q * 4;
        const int j2 = (j + 2 > NIN_ - 2) ? (NIN_ - 2) : (j + 2);
        #pragma unroll
        for (int oo = 0; oo < 4; ++oo) {
            wA[oo] = *reinterpret_cast<const float2*>(wb + oo * NIN_ + j);
            wB[oo] = *reinterpret_cast<const float2*>(wb + oo * NIN_ + j2);
        }
    }

    // ======== phase A: zero xe, barrier, scatter ========
    (&xe[0][0])[tid] = 0.0f;
    barrier_lds();
    if (aj0 < NIN_) atomicAdd(&xe[ar0][aj0], ax0);
    if (aj1 < NIN_) atomicAdd(&xe[ar1][aj1], ax1);
    if (aj2 < NIN_) atomicAdd(&xe[ar2][aj2], ax2);
    barrier_lds();

    // ======== phase B: h1 = elu(xe @ W0^T + b0), streamed W0 ========
    const float* wcp = W1 + (g * 4) * H1_ + q * 4;   // phase-C weight base
    float4 wc[4];
    {
        float acc[4][4] = {};   // [oo][r]
        #pragma unroll
        for (int jj = 0; jj < 4; ++jj) {
            float2 nA[4], nB[4];
            if (jj < 3) {
                const int j = q * 4 + (jj + 1) * 32;
                const int j2 = (j + 2 > NIN_ - 2) ? (NIN_ - 2) : (j + 2);
                #pragma unroll
                for (int oo = 0; oo < 4; ++oo) {
                    nA[oo] = *reinterpret_cast<const float2*>(wb + oo * NIN_ + j);
                    nB[oo] = *reinterpret_cast<const float2*>(wb + oo * NIN_ + j2);
                }
            }
            const int j = q * 4 + jj * 32;
            float4 a[RPB];
            #pragma unroll
            for (int r = 0; r < RPB; ++r)
                a[r] = *reinterpret_cast<const float4*>(&xe[r][j]);  // pad cols are 0
            #pragma unroll
            for (int oo = 0; oo < 4; ++oo)
                #pragma unroll
                for (int r = 0; r < RPB; ++r) {
                    acc[oo][r] = fmaf(wA[oo].x, a[r].x, acc[oo][r]);
                    acc[oo][r] = fmaf(wA[oo].y, a[r].y, acc[oo][r]);
                    acc[oo][r] = fmaf(wB[oo].x, a[r].z, acc[oo][r]);
                    acc[oo][r] = fmaf(wB[oo].y, a[r].w, acc[oo][r]);
                }
            if (jj < 3) {
                #pragma unroll
                for (int oo = 0; oo < 4; ++oo) { wA[oo] = nA[oo]; wB[oo] = nB[oo]; }
            }
        }
        // pre-issue phase C's first weights (covered by reduce + barrier)
        #pragma unroll
        for (int oo = 0; oo < 4; ++oo)
            wc[oo] = *reinterpret_cast<const float4*>(wcp + oo * H1_);

        #pragma unroll
        for (int oo = 0; oo < 4; ++oo)
            #pragma unroll
            for (int r = 0; r < RPB; ++r) acc[oo][r] = qsum8(acc[oo][r]);
        // lane q writes flat accs 2q, 2q+1 (flat = oo*4 + r)
        float v0 = acc[0][0], v1 = acc[0][1];
        #pragma unroll
        for (int i = 1; i < 8; ++i) {
            v0 = (q == i) ? acc[(2 * i) >> 2][(2 * i) & 3]         : v0;
            v1 = (q == i) ? acc[(2 * i + 1) >> 2][(2 * i + 1) & 3] : v1;
        }
        const int oo = q >> 1, r0 = (q & 1) * 2;
        const float bias = (oo == 0) ? b0v.x : (oo == 1) ? b0v.y : (oo == 2) ? b0v.z : b0v.w;
        const int o = g * 4 + oo;
        h1s[r0][o]     = elu1(v0 + bias);
        h1s[r0 + 1][o] = elu1(v1 + bias);
    }
    barrier_lds();

    // ======== phase C: h2 = elu(h1 @ W1^T + b1), streamed W1 ========
    const float* wdp = W2 + (gD * 2) * H2_ + q * 4;  // phase-D weight base
    float4 wd[2];
    {
        float acc[4][4] = {};
        #pragma unroll
        for (int jj = 0; jj < 8; ++jj) {
            float4 nc[4];
            if (jj < 7) {
                #pragma unroll
                for (int oo = 0; oo < 4; ++oo)
                    nc[oo] = *reinterpret_cast<const float4*>(wcp + oo * H1_ + (jj + 1) * 32);
            }
            const int j = q * 4 + jj * 32;
            float4 a[RPB];
            #pragma unroll
            for (int r = 0; r < RPB; ++r)
                a[r] = *reinterpret_cast<const float4*>(&h1s[r][j]);
            #pragma unroll
            for (int oo = 0; oo < 4; ++oo)
                #pragma unroll
                for (int r = 0; r < RPB; ++r) {
                    acc[oo][r] = fmaf(wc[oo].x, a[r].x, acc[oo][r]);
                    acc[oo][r] = fmaf(wc[oo].y, a[r].y, acc[oo][r]);
                    acc[oo][r] = fmaf(wc[oo].z, a[r].z, acc[oo][r]);
                    acc[oo][r] = fmaf(wc[oo].w, a[r].w, acc[oo][r]);
                }
            if (jj < 7) {
                #pragma unroll
                for (int oo = 0; oo < 4; ++oo) wc[oo] = nc[oo];
            }
        }
        // pre-issue phase D's first weights
        wd[0] = *reinterpret_cast<const float4*>(wdp);
        wd[1] = *reinterpret_cast<const float4*>(wdp + H2_);

        #pragma unroll
        for (int oo = 0; oo < 4; ++oo)
            #pragma unroll
            for (int r = 0; r < RPB; ++r) acc[oo][r] = qsum8(acc[oo][r]);
        float v0 = acc[0][0], v1 = acc[0][1];
        #pragma unroll
        for (int i = 1; i < 8; ++i) {
            v0 = (q == i) ? acc[(2 * i) >> 2][(2 * i) & 3]         : v0;
            v1 = (q == i) ? acc[(2 * i + 1) >> 2][(2 * i + 1) & 3] : v1;
        }
        const int oo = q >> 1, r0 = (q & 1) * 2;
        const float bias = (oo == 0) ? b1v.x : (oo == 1) ? b1v.y : (oo == 2) ? b1v.z : b1v.w;
        const int o = g * 4 + oo;
        h2s[r0][o]     = elu1(v0 + bias);
        h2s[r0 + 1][o] = elu1(v1 + bias);
    }
    barrier_lds();

    // ======== phase D: ts[r][j] = h2s[r].W2[j,:] + b2[j], streamed W2 ======
    {
        float acc[2][4] = {};
        #pragma unroll
        for (int jj = 0; jj < 8; ++jj) {
            float4 nd[2];
            if (jj < 7) {
                nd[0] = *reinterpret_cast<const float4*>(wdp + (jj + 1) * 32);
                nd[1] = *reinterpret_cast<const float4*>(wdp + H2_ + (jj + 1) * 32);
            }
            const int j = q * 4 + jj * 32;
            float4 a[RPB];
            #pragma unroll
            for (int r = 0; r < RPB; ++r)
                a[r] = *reinterpret_cast<const float4*>(&h2s[r][j]);
            #pragma unroll
            for (int oo = 0; oo < 2; ++oo)
                #pragma unroll
                for (int r = 0; r < RPB; ++r) {
                    acc[oo][r] = fmaf(wd[oo].x, a[r].x, acc[oo][r]);
                    acc[oo][r] = fmaf(wd[oo].y, a[r].y, acc[oo][r]);
                    acc[oo][r] = fmaf(wd[oo].z, a[r].z, acc[oo][r]);
                    acc[oo][r] = fmaf(wd[oo].w, a[r].w, acc[oo][r]);
                }
            if (jj < 7) { wd[0] = nd[0]; wd[1] = nd[1]; }
        }
        #pragma unroll
        for (int oo = 0; oo < 2; ++oo)
            #pragma unroll
            for (int r = 0; r < RPB; ++r) acc[oo][r] = qsum8(acc[oo][r]);
        float v = acc[0][0];
        #pragma unroll
        for (int i = 1; i < 8; ++i) v = (q == i) ? acc[i >> 2][i & 3] : v;
        const int oo = q >> 2, rr = q & 3;
        if (g < 63) ts[rr][g * 2 + oo] = v + (oo ? b2v.y : b2v.x);
        else        ts[rr][126 + oo]   = 0.0f;
    }
    barrier_lds();

    // ======== phase E: out[b,o] = sum_k ts[r][ej_k] ========
    if (tid < RPB * NOUT_) {
        const int r = tid / NOUT_, o = tid - r * NOUT_;
        out[(row0 + r) * NOUT_ + o] = ts[r][ej0] + ts[r][ej1] + ts[r][ej2];
    }
}

extern "C" void kernel_launch(void* const* d_in, const int* in_sizes, int n_in,
                              void* d_out, int out_size, void* d_ws, size_t ws_size,
                              hipStream_t stream) {
    const float* x   = (const float*)d_in[0];
    const float* W0  = (const float*)d_in[1];
    const float* b0  = (const float*)d_in[2];
    const float* W1  = (const float*)d_in[3];
    const float* b1  = (const float*)d_in[4];
    const float* W2  = (const float*)d_in[5];
    const float* b2  = (const float*)d_in[6];
    const int*  iidx = (const int*)d_in[7];
    const int*  oidx = (const int*)d_in[8];
    float* out = (float*)d_out;

    bim_fused<<<B_ / RPB, TPB, 0, stream>>>(x, W0, b0, W1, b1, W2, b2, iidx, oidx, out);
}

// Round 7
// 15.620 us; speedup vs baseline: 2.7085x; 1.0135x over previous
//
#include <hip/hip_runtime.h>

#define B_    1024
#define NIN_  126
#define NOUT_ 126
#define K_    3
#define H1_   256
#define H2_   256
#define RPB   4
#define TPB   512    // 8 waves, 1 block/CU, grid = 256

__device__ __forceinline__ float elu1(float v) { return v > 0.0f ? v : expm1f(v); }

// DPP quad_perm add (VALU pipe)
template<int CTRL>
__device__ __forceinline__ float dpp_add(float v) {
    int s = __builtin_amdgcn_update_dpp(0, __float_as_int(v), CTRL, 0xF, 0xF, true);
    return v + __int_as_float(s);
}
// sum over 8 consecutive lanes: xor1,xor2 via DPP, xor4 via ds_swizzle
__device__ __forceinline__ float qsum8(float v) {
    v = dpp_add<0xB1>(v);
    v = dpp_add<0x4E>(v);
    int s = __builtin_amdgcn_ds_swizzle(__float_as_int(v), 0x101F);
    return v + __int_as_float(s);
}

// barrier draining only LDS/SMEM ops; global loads stay in flight
__device__ __forceinline__ void barrier_lds() {
    asm volatile("s_waitcnt lgkmcnt(0)\n\ts_barrier" ::: "memory");
}

__global__ __launch_bounds__(TPB) void bim_fused(
    const float* __restrict__ x,  const float* __restrict__ W0,
    const float* __restrict__ b0, const float* __restrict__ W1,
    const float* __restrict__ b1, const float* __restrict__ W2,
    const float* __restrict__ b2, const int*  __restrict__ iidx,
    const int*  __restrict__ oidx, float* __restrict__ out)
{
    __shared__ float xe [RPB][128];   // scattered x; cols 126/127 stay 0
    __shared__ float h1s[RPB][H1_];
    __shared__ float h2s[RPB][H2_];
    __shared__ float ts [RPB][128];   // b2 folded in; cols 126/127 zeroed

    const int tid  = threadIdx.x;
    const int row0 = blockIdx.x * RPB;
    const int q    = tid & 7;    // k-split lane
    const int g    = tid >> 3;   // group 0..63

    // ---- phase-A operands first (phase A critical path) ----
    int aj0, aj1, aj2, ar0, ar1, ar2; float ax0, ax1, ax2;
    {
        const int n0 = tid;
        ar0 = n0 / (NIN_ * K_); const int m0 = n0 - ar0 * (NIN_ * K_);
        aj0 = iidx[(row0 + ar0) * (NIN_ * K_) + m0];
        ax0 = x[(row0 + ar0) * NIN_ + m0 / K_];
        const int n1 = tid + TPB;                 // < 1512 always
        ar1 = n1 / (NIN_ * K_); const int m1 = n1 - ar1 * (NIN_ * K_);
        aj1 = iidx[(row0 + ar1) * (NIN_ * K_) + m1];
        ax1 = x[(row0 + ar1) * NIN_ + m1 / K_];
        const int n2 = tid + 2 * TPB;
        const int n2c = n2 < RPB * NIN_ * K_ ? n2 : 0;
        ar2 = n2c / (NIN_ * K_); const int m2 = n2c - ar2 * (NIN_ * K_);
        aj2 = iidx[(row0 + ar2) * (NIN_ * K_) + m2];
        ax2 = x[(row0 + ar2) * NIN_ + m2 / K_];
        if (n2 >= RPB * NIN_ * K_) aj2 = NIN_;
    }

    // ---- W0 in FULL (64 VGPRs), latency covered by phase A ----
    const float* wb = W0 + (g * 4) * NIN_;
    float2 wA[4][4], wB[4][4];   // [jj][oo]
    #pragma unroll
    for (int jj = 0; jj < 4; ++jj) {
        const int j  = q * 4 + jj * 32;
        const int j2 = (j + 2 > NIN_ - 2) ? (NIN_ - 2) : (j + 2); // clamp; xe pad=0 kills garbage
        #pragma unroll
        for (int oo = 0; oo < 4; ++oo) {
            wA[jj][oo] = *reinterpret_cast<const float2*>(wb + oo * NIN_ + j);
            wB[jj][oo] = *reinterpret_cast<const float2*>(wb + oo * NIN_ + j2);
        }
    }

    // ---- phase-E indices + biases (small) ----
    int ej0, ej1, ej2;
    {
        const int t = tid < RPB * NOUT_ ? tid : 0;
        const int r = t / NOUT_, o = t - r * NOUT_;
        const int base = (row0 + r) * (NOUT_ * K_) + o * K_;
        ej0 = oidx[base]; ej1 = oidx[base + 1]; ej2 = oidx[base + 2];
    }
    const float4 b0v = *reinterpret_cast<const float4*>(b0 + g * 4);
    const float4 b1v = *reinterpret_cast<const float4*>(b1 + g * 4);
    const int    gD  = (g < 63) ? g : 0;
    const float2 b2v = *reinterpret_cast<const float2*>(b2 + gD * 2);

    // ======== phase A: zero xe, barrier, scatter ========
    (&xe[0][0])[tid] = 0.0f;
    barrier_lds();
    if (aj0 < NIN_) atomicAdd(&xe[ar0][aj0], ax0);
    if (aj1 < NIN_) atomicAdd(&xe[ar1][aj1], ax1);
    if (aj2 < NIN_) atomicAdd(&xe[ar2][aj2], ax2);

    // ---- issue W1 FIRST HALF (64 VGPRs) before the barrier ----
    const float* wcp = W1 + (g * 4) * H1_ + q * 4;
    float4 wc1[4][4];   // [jj][oo], jj = 0..3
    #pragma unroll
    for (int jj = 0; jj < 4; ++jj)
        #pragma unroll
        for (int oo = 0; oo < 4; ++oo)
            wc1[jj][oo] = *reinterpret_cast<const float4*>(wcp + oo * H1_ + jj * 32);
    barrier_lds();

    // ======== phase B: h1 = elu(xe @ W0^T + b0) ========
    float4 wc2[4][4];   // W1 second half, issued mid-phase
    {
        float acc[4][4] = {};   // [oo][r]
        #pragma unroll
        for (int jj = 0; jj < 2; ++jj) {
            const int j = q * 4 + jj * 32;
            float4 a[RPB];
            #pragma unroll
            for (int r = 0; r < RPB; ++r)
                a[r] = *reinterpret_cast<const float4*>(&xe[r][j]);
            #pragma unroll
            for (int oo = 0; oo < 4; ++oo)
                #pragma unroll
                for (int r = 0; r < RPB; ++r) {
                    acc[oo][r] = fmaf(wA[jj][oo].x, a[r].x, acc[oo][r]);
                    acc[oo][r] = fmaf(wA[jj][oo].y, a[r].y, acc[oo][r]);
                    acc[oo][r] = fmaf(wB[jj][oo].x, a[r].z, acc[oo][r]);
                    acc[oo][r] = fmaf(wB[jj][oo].y, a[r].w, acc[oo][r]);
                }
        }
        // ---- issue W1 SECOND HALF (64 VGPRs; wA/wB half dead by now) ----
        #pragma unroll
        for (int jj = 0; jj < 4; ++jj)
            #pragma unroll
            for (int oo = 0; oo < 4; ++oo)
                wc2[jj][oo] = *reinterpret_cast<const float4*>(wcp + oo * H1_ + (jj + 4) * 32);
        #pragma unroll
        for (int jj = 2; jj < 4; ++jj) {
            const int j = q * 4 + jj * 32;
            float4 a[RPB];
            #pragma unroll
            for (int r = 0; r < RPB; ++r)
                a[r] = *reinterpret_cast<const float4*>(&xe[r][j]);
            #pragma unroll
            for (int oo = 0; oo < 4; ++oo)
                #pragma unroll
                for (int r = 0; r < RPB; ++r) {
                    acc[oo][r] = fmaf(wA[jj][oo].x, a[r].x, acc[oo][r]);
                    acc[oo][r] = fmaf(wA[jj][oo].y, a[r].y, acc[oo][r]);
                    acc[oo][r] = fmaf(wB[jj][oo].x, a[r].z, acc[oo][r]);
                    acc[oo][r] = fmaf(wB[jj][oo].y, a[r].w, acc[oo][r]);
                }
        }
        #pragma unroll
        for (int oo = 0; oo < 4; ++oo)
            #pragma unroll
            for (int r = 0; r < RPB; ++r) acc[oo][r] = qsum8(acc[oo][r]);
        float v0 = acc[0][0], v1 = acc[0][1];
        #pragma unroll
        for (int i = 1; i < 8; ++i) {
            v0 = (q == i) ? acc[(2 * i) >> 2][(2 * i) & 3]         : v0;
            v1 = (q == i) ? acc[(2 * i + 1) >> 2][(2 * i + 1) & 3] : v1;
        }
        const int oo = q >> 1, r0 = (q & 1) * 2;
        const float bias = (oo == 0) ? b0v.x : (oo == 1) ? b0v.y : (oo == 2) ? b0v.z : b0v.w;
        const int o = g * 4 + oo;
        h1s[r0][o]     = elu1(v0 + bias);
        h1s[r0 + 1][o] = elu1(v1 + bias);
    }
    barrier_lds();

    // ======== phase C: h2 = elu(h1 @ W1^T + b1) ========
    const float* wdp = W2 + (gD * 2) * H2_ + q * 4;
    float4 wd[8][2];    // W2 in full, issued mid-phase
    {
        float acc[4][4] = {};
        #pragma unroll
        for (int jj = 0; jj < 6; ++jj) {
            const float4* wrow = (jj < 4) ? wc1[jj] : wc2[jj - 4];
            const int j = q * 4 + jj * 32;
            float4 a[RPB];
            #pragma unroll
            for (int r = 0; r < RPB; ++r)
                a[r] = *reinterpret_cast<const float4*>(&h1s[r][j]);
            #pragma unroll
            for (int oo = 0; oo < 4; ++oo)
                #pragma unroll
                for (int r = 0; r < RPB; ++r) {
                    acc[oo][r] = fmaf(wrow[oo].x, a[r].x, acc[oo][r]);
                    acc[oo][r] = fmaf(wrow[oo].y, a[r].y, acc[oo][r]);
                    acc[oo][r] = fmaf(wrow[oo].z, a[r].z, acc[oo][r]);
                    acc[oo][r] = fmaf(wrow[oo].w, a[r].w, acc[oo][r]);
                }
        }
        // ---- issue ALL W2 (64 VGPRs; wc1 dead, wc2 mostly dead) ----
        #pragma unroll
        for (int jj = 0; jj < 8; ++jj)
            #pragma unroll
            for (int oo = 0; oo < 2; ++oo)
                wd[jj][oo] = *reinterpret_cast<const float4*>(wdp + oo * H2_ + jj * 32);
        #pragma unroll
        for (int jj = 6; jj < 8; ++jj) {
            const float4* wrow = wc2[jj - 4];
            const int j = q * 4 + jj * 32;
            float4 a[RPB];
            #pragma unroll
            for (int r = 0; r < RPB; ++r)
                a[r] = *reinterpret_cast<const float4*>(&h1s[r][j]);
            #pragma unroll
            for (int oo = 0; oo < 4; ++oo)
                #pragma unroll
                for (int r = 0; r < RPB; ++r) {
                    acc[oo][r] = fmaf(wrow[oo].x, a[r].x, acc[oo][r]);
                    acc[oo][r] = fmaf(wrow[oo].y, a[r].y, acc[oo][r]);
                    acc[oo][r] = fmaf(wrow[oo].z, a[r].z, acc[oo][r]);
                    acc[oo][r] = fmaf(wrow[oo].w, a[r].w, acc[oo][r]);
                }
        }
        #pragma unroll
        for (int oo = 0; oo < 4; ++oo)
            #pragma unroll
            for (int r = 0; r < RPB; ++r) acc[oo][r] = qsum8(acc[oo][r]);
        float v0 = acc[0][0], v1 = acc[0][1];
        #pragma unroll
        for (int i = 1; i < 8; ++i) {
            v0 = (q == i) ? acc[(2 * i) >> 2][(2 * i) & 3]         : v0;
            v1 = (q == i) ? acc[(2 * i + 1) >> 2][(2 * i + 1) & 3] : v1;
        }
        const int oo = q >> 1, r0 = (q & 1) * 2;
        const float bias = (oo == 0) ? b1v.x : (oo == 1) ? b1v.y : (oo == 2) ? b1v.z : b1v.w;
        const int o = g * 4 + oo;
        h2s[r0][o]     = elu1(v0 + bias);
        h2s[r0 + 1][o] = elu1(v1 + bias);
    }
    barrier_lds();

    // ======== phase D: ts[r][j] = h2s[r].W2[j,:] + b2[j] ========
    {
        float acc[2][4] = {};
        #pragma unroll
        for (int jj = 0; jj < 8; ++jj) {
            const int j = q * 4 + jj * 32;
            float4 a[RPB];
            #pragma unroll
            for (int r = 0; r < RPB; ++r)
                a[r] = *reinterpret_cast<const float4*>(&h2s[r][j]);
            #pragma unroll
            for (int oo = 0; oo < 2; ++oo)
                #pragma unroll
                for (int r = 0; r < RPB; ++r) {
                    acc[oo][r] = fmaf(wd[jj][oo].x, a[r].x, acc[oo][r]);
                    acc[oo][r] = fmaf(wd[jj][oo].y, a[r].y, acc[oo][r]);
                    acc[oo][r] = fmaf(wd[jj][oo].z, a[r].z, acc[oo][r]);
                    acc[oo][r] = fmaf(wd[jj][oo].w, a[r].w, acc[oo][r]);
                }
        }
        #pragma unroll
        for (int oo = 0; oo < 2; ++oo)
            #pragma unroll
            for (int r = 0; r < RPB; ++r) acc[oo][r] = qsum8(acc[oo][r]);
        float v = acc[0][0];
        #pragma unroll
        for (int i = 1; i < 8; ++i) v = (q == i) ? acc[i >> 2][i & 3] : v;
        const int oo = q >> 2, rr = q & 3;
        if (g < 63) ts[rr][g * 2 + oo] = v + (oo ? b2v.y : b2v.x);
        else        ts[rr][126 + oo]   = 0.0f;
    }
    barrier_lds();

    // ======== phase E: out[b,o] = sum_k ts[r][ej_k] ========
    if (tid < RPB * NOUT_) {
        const int r = tid / NOUT_, o = tid - r * NOUT_;
        out[(row0 + r) * NOUT_ + o] = ts[r][ej0] + ts[r][ej1] + ts[r][ej2];
    }
}

extern "C" void kernel_launch(void* const* d_in, const int* in_sizes, int n_in,
                              void* d_out, int out_size, void* d_ws, size_t ws_size,
                              hipStream_t stream) {
    const float* x   = (const float*)d_in[0];
    const float* W0  = (const float*)d_in[1];
    const float* b0  = (const float*)d_in[2];
    const float* W1  = (const float*)d_in[3];
    const float* b1  = (const float*)d_in[4];
    const float* W2  = (const float*)d_in[5];
    const float* b2  = (const float*)d_in[6];
    const int*  iidx = (const int*)d_in[7];
    const int*  oidx = (const int*)d_in[8];
    float* out = (float*)d_out;

    bim_fused<<<B_ / RPB, TPB, 0, stream>>>(x, W0, b0, W1, b1, W2, b2, iidx, oidx, out);
}